// Round 8
// baseline (180.543 us; speedup 1.0000x reference)
//
#include <hip/hip_runtime.h>
#include <hip/hip_bf16.h>

typedef __attribute__((ext_vector_type(8))) short bf16x8;
typedef __attribute__((ext_vector_type(4))) float f32x4;

#define N_TOKENS 16384
#define DIM 4096
#define TOKB 32      // tokens per block
#define KQ 1024      // K quarter per wave
#define N_EXP 64

// d_out layout (all float32):
//   [0, 32768)              topk_experts as float  [token][2]
//   [32768, 65536)          combine_weight         [token][2]
//   [65536, 65536+1048576)  scores                 [token][64]
//   [1114112]               load_balance_loss
//   [1114113]               z_loss
#define OFF_W   (N_TOKENS * 2)
#define OFF_S   (N_TOKENS * 4)
#define OFF_LBL (N_TOKENS * 4 + N_TOKENS * N_EXP)
#define OFF_Z   (OFF_LBL + 1)

// ws layout (floats): [0..63] me partials, [64..127] ce partials, [128] z partial,
// [512 ..) w_hi as ushort[64*4096] (512 KB), then w_lo as ushort[64*4096] (512 KB)
#define WS_WHI_F 512
#define WS_WLO_F (512 + (N_EXP * DIM) / 2)

// split one fp32 into hi bf16 + lo bf16 (RNE both): f ≈ hi + lo, |err| ~ 2^-17 |f|
__device__ __forceinline__ void split2(float f, short* hi, short* lo) {
  unsigned short h = __builtin_bit_cast(unsigned short, __float2bfloat16(f));
  float hf = __uint_as_float(((unsigned)h) << 16);
  unsigned short l = __builtin_bit_cast(unsigned short, __float2bfloat16(f - hf));
  *hi = (short)h;
  *lo = (short)l;
}

__device__ __forceinline__ void split8(const float4& f0, const float4& f1,
                                       bf16x8& hi, bf16x8& lo) {
  short h[8], l[8];
  split2(f0.x, &h[0], &l[0]);
  split2(f0.y, &h[1], &l[1]);
  split2(f0.z, &h[2], &l[2]);
  split2(f0.w, &h[3], &l[3]);
  split2(f1.x, &h[4], &l[4]);
  split2(f1.y, &h[5], &l[5]);
  split2(f1.z, &h[6], &l[6]);
  split2(f1.w, &h[7], &l[7]);
#pragma unroll
  for (int i = 0; i < 8; ++i) { hi[i] = h[i]; lo[i] = l[i]; }
}

// pre-pass: w fp32 -> separate bf16 hi / lo planes (read 1 MB, write 1 MB, ~3 us)
__global__ __launch_bounds__(256) void split_w_kernel(
    const float* __restrict__ w,
    unsigned short* __restrict__ whi, unsigned short* __restrict__ wlo)
{
  const int i = blockIdx.x * 256 + threadIdx.x;  // 0 .. 64*4096-1
  float f = w[i];
  unsigned short h = __builtin_bit_cast(unsigned short, __float2bfloat16(f));
  float hf = __uint_as_float(((unsigned)h) << 16);
  unsigned short l = __builtin_bit_cast(unsigned short, __float2bfloat16(f - hf));
  whi[i] = h;
  wlo[i] = l;
}

__global__ __launch_bounds__(512) void router_kernel(
    const float* __restrict__ x,
    const unsigned short* __restrict__ whi, const unsigned short* __restrict__ wlo,
    float* __restrict__ out, float* __restrict__ ws)
{
  __shared__ float lbuf[4][TOKB * 65];  // per-K-quarter partial logits; [0] also scores
  const int tid  = threadIdx.x;
  const int lane = tid & 63;
  const int wv   = __builtin_amdgcn_readfirstlane(tid >> 6);  // 0..7, wave-uniform
  const int g    = wv & 1;   // token sub-group (16 tokens each)
  const int kq   = wv >> 1;  // K quarter: 0..3
  const int half = lane >> 4;  // 0..3  -> k-subblock of 8
  const int r15  = lane & 15;

  const int tokL = g * 16;                         // local token base (within block's 32)
  const int tok0 = blockIdx.x * TOKB + tokL;       // global token base for this wave

  // A fragment source: x[tok0 + r15][kq*KQ + half*8 + j + k0]
  const float* xp = x + (size_t)(tok0 + r15) * DIM + kq * KQ + half * 8;
  // B fragment sources (bf16 planes): w?[n*16 + r15][kq*KQ + half*8 + j + k0]
  const unsigned short* whp = whi + (size_t)r15 * DIM + kq * KQ + half * 8;
  const unsigned short* wlp = wlo + (size_t)r15 * DIM + kq * KQ + half * 8;
#define WHROW(n) (whp + (size_t)(n) * 16 * DIM)
#define WLROW(n) (wlp + (size_t)(n) * 16 * DIM)

  f32x4 acc[4];
#pragma unroll
  for (int n = 0; n < 4; ++n) acc[n] = (f32x4){0.f, 0.f, 0.f, 0.f};

  // x: 2-deep register pipeline
  float4 x0a = *(const float4*)(xp);
  float4 x0b = *(const float4*)(xp + 4);
  float4 x1a = *(const float4*)(xp + 32);
  float4 x1b = *(const float4*)(xp + 36);
  // w: 1-deep (L2-resident stream)
  bf16x8 cbh[4], cbl[4];
#pragma unroll
  for (int n = 0; n < 4; ++n) {
    cbh[n] = *(const bf16x8*)(WHROW(n));
    cbl[n] = *(const bf16x8*)(WLROW(n));
  }

  for (int k0 = 0; k0 < KQ; k0 += 32) {
    const int knx = (k0 + 64 < KQ) ? (k0 + 64) : k0;  // clamped 2-ahead
    const int knw = (k0 + 32 < KQ) ? (k0 + 32) : k0;  // clamped 1-ahead
    // ---- load cluster (issue early) ----
    float4 x2a = *(const float4*)(xp + knx);
    float4 x2b = *(const float4*)(xp + knx + 4);
    bf16x8 nbh[4], nbl[4];
#pragma unroll
    for (int n = 0; n < 4; ++n) {
      nbh[n] = *(const bf16x8*)(WHROW(n) + knw);
      nbl[n] = *(const bf16x8*)(WLROW(n) + knw);
    }
    // pin: loads above may not be sunk below this point
    __builtin_amdgcn_sched_barrier(0);

    // ---- compute cluster on current regs ----
    bf16x8 a_hi, a_lo;
    split8(x0a, x0b, a_hi, a_lo);

#pragma unroll
    for (int n = 0; n < 4; ++n)
      acc[n] = __builtin_amdgcn_mfma_f32_16x16x32_bf16(a_hi, cbh[n], acc[n], 0, 0, 0);
#pragma unroll
    for (int n = 0; n < 4; ++n)
      acc[n] = __builtin_amdgcn_mfma_f32_16x16x32_bf16(a_lo, cbh[n], acc[n], 0, 0, 0);
#pragma unroll
    for (int n = 0; n < 4; ++n)
      acc[n] = __builtin_amdgcn_mfma_f32_16x16x32_bf16(a_hi, cbl[n], acc[n], 0, 0, 0);

    // ---- rotate pipeline ----
    x0a = x1a; x0b = x1b; x1a = x2a; x1b = x2b;
#pragma unroll
    for (int n = 0; n < 4; ++n) { cbh[n] = nbh[n]; cbl[n] = nbl[n]; }
  }

  // scatter partial logits to LDS.  C layout: row = half*4 + r (token), col = r15 (expert)
  float* dst = lbuf[kq];
#pragma unroll
  for (int n = 0; n < 4; ++n) {
#pragma unroll
    for (int r = 0; r < 4; ++r) {
      dst[(tokL + half * 4 + r) * 65 + n * 16 + r15] = acc[n][r];
    }
  }
  __syncthreads();

  // combine the four K quarters: 2048 elems over 512 threads
  for (int i = tid; i < TOKB * 64; i += 512) {
    const int t = i >> 6, e = i & 63;
    lbuf[0][t * 65 + e] += lbuf[1][t * 65 + e] + lbuf[2][t * 65 + e] + lbuf[3][t * 65 + e];
  }
  __syncthreads();

  if (wv == 0 && lane < TOKB) {
    // lane owns one token: full softmax + top-2 + z-loss
    const int token = blockIdx.x * TOKB + lane;
    float v[64];
#pragma unroll
    for (int e = 0; e < 64; ++e) v[e] = lbuf[0][lane * 65 + e];
    float m = v[0];
#pragma unroll
    for (int e = 1; e < 64; ++e) m = fmaxf(m, v[e]);
    float sum = 0.f;
#pragma unroll
    for (int e = 0; e < 64; ++e) { v[e] = expf(v[e] - m); sum += v[e]; }
    const float inv = 1.0f / sum;
    float m1 = -1.f, m2 = -1.f;
    int   i1 = 0,    i2 = 0;
#pragma unroll
    for (int e = 0; e < 64; ++e) {
      float sc = v[e] * inv;
      lbuf[0][lane * 65 + e] = sc;
      if (sc > m1)      { m2 = m1; i2 = i1; m1 = sc; i1 = e; }
      else if (sc > m2) { m2 = sc; i2 = e; }
    }
    out[2 * token]         = (float)i1;
    out[2 * token + 1]     = (float)i2;
    out[OFF_W + 2 * token]     = m1;
    out[OFF_W + 2 * token + 1] = m2;

    float lse = m + logf(sum);
    float z = lse * lse;
#pragma unroll
    for (int off = 16; off > 0; off >>= 1) z += __shfl_down(z, off);
    if (lane == 0) atomicAdd(ws + 128, z);
  }
  __syncthreads();

  // coalesced scores store for this block's 32 tokens
  float* outS = out + OFF_S + (size_t)blockIdx.x * TOKB * 64;
  for (int i = tid; i < TOKB * 64; i += 512) {
    outS[i] = lbuf[0][(i >> 6) * 65 + (i & 63)];
  }

  // per-expert partial me / ce for this block's tokens (expert = lane)
  if (wv == 0) {
    float sm = 0.f, cn = 0.f;
#pragma unroll
    for (int t = 0; t < TOKB; ++t) {
      float sc = lbuf[0][t * 65 + lane];
      sm += sc;
      cn += (sc > 0.f) ? 1.f : 0.f;
    }
    atomicAdd(ws + lane, sm);
    atomicAdd(ws + 64 + lane, cn);
  }
}

__global__ void finalize_kernel(const float* __restrict__ ws, float* __restrict__ out) {
  const int l = threadIdx.x;  // 64 threads
  const float invT = 1.0f / (float)N_TOKENS;
  float me = ws[l] * invT;
  float ce = ws[64 + l] * invT;
  float p = me * ce;
#pragma unroll
  for (int off = 32; off > 0; off >>= 1) p += __shfl_down(p, off);
  if (l == 0) {
    out[OFF_LBL] = p * (float)N_EXP;
    out[OFF_Z]   = ws[128] * invT;
  }
}

extern "C" void kernel_launch(void* const* d_in, const int* in_sizes, int n_in,
                              void* d_out, int out_size, void* d_ws, size_t ws_size,
                              hipStream_t stream) {
  const float* x = (const float*)d_in[0];
  const float* w = (const float*)d_in[1];
  float* out = (float*)d_out;
  float* ws  = (float*)d_ws;
  unsigned short* whi = (unsigned short*)(ws + WS_WHI_F);
  unsigned short* wlo = (unsigned short*)(ws + WS_WLO_F);

  (void)hipMemsetAsync(d_ws, 0, 129 * sizeof(float), stream);
  split_w_kernel<<<(N_EXP * DIM) / 256, 256, 0, stream>>>(w, whi, wlo);
  router_kernel<<<N_TOKENS / TOKB, 512, 0, stream>>>(x, whi, wlo, out, ws);
  finalize_kernel<<<1, 64, 0, stream>>>(ws, out);
}

// Round 9
// 109.945 us; speedup vs baseline: 1.6421x; 1.6421x over previous
//
#include <hip/hip_runtime.h>
#include <hip/hip_bf16.h>

typedef __attribute__((ext_vector_type(8))) short bf16x8;
typedef __attribute__((ext_vector_type(4))) float f32x4;

#define N_TOKENS 16384
#define DIM 4096
#define TOKB 32            // tokens per block
#define BK 128             // K per staged tile
#define NIT (DIM / BK)     // 32 iterations
#define LDX 136            // bf16 row stride in LDS (128 + 8 pad)
#define XBUF (TOKB * LDX)  // 4352 ushorts per plane-buffer
#define N_EXP 64

// d_out layout (all float32):
//   [0, 32768)              topk_experts as float  [token][2]
//   [32768, 65536)          combine_weight         [token][2]
//   [65536, 65536+1048576)  scores                 [token][64]
//   [1114112]               load_balance_loss
//   [1114113]               z_loss
#define OFF_W   (N_TOKENS * 2)
#define OFF_S   (N_TOKENS * 4)
#define OFF_LBL (N_TOKENS * 4 + N_TOKENS * N_EXP)
#define OFF_Z   (OFF_LBL + 1)

// ws layout (floats): [0..63] me partials, [64..127] ce partials, [128] z partial,
// [512 ..) w_hi as ushort[64*4096] (512 KB), then w_lo as ushort[64*4096] (512 KB)
#define WS_WHI_F 512
#define WS_WLO_F (512 + (N_EXP * DIM) / 2)

// split one fp32 into hi bf16 + lo bf16 (RNE both): f ≈ hi + lo, |err| ~ 2^-17 |f|
__device__ __forceinline__ void split2(float f, short* hi, short* lo) {
  unsigned short h = __builtin_bit_cast(unsigned short, __float2bfloat16(f));
  float hf = __uint_as_float(((unsigned)h) << 16);
  unsigned short l = __builtin_bit_cast(unsigned short, __float2bfloat16(f - hf));
  *hi = (short)h;
  *lo = (short)l;
}

__device__ __forceinline__ void split8(const float4& f0, const float4& f1,
                                       bf16x8& hi, bf16x8& lo) {
  short h[8], l[8];
  split2(f0.x, &h[0], &l[0]);
  split2(f0.y, &h[1], &l[1]);
  split2(f0.z, &h[2], &l[2]);
  split2(f0.w, &h[3], &l[3]);
  split2(f1.x, &h[4], &l[4]);
  split2(f1.y, &h[5], &l[5]);
  split2(f1.z, &h[6], &l[6]);
  split2(f1.w, &h[7], &l[7]);
#pragma unroll
  for (int i = 0; i < 8; ++i) { hi[i] = h[i]; lo[i] = l[i]; }
}

// pre-pass: w fp32 -> separate bf16 hi / lo planes (1 MB total, ~3 us)
__global__ __launch_bounds__(256) void split_w_kernel(
    const float* __restrict__ w,
    unsigned short* __restrict__ whi, unsigned short* __restrict__ wlo)
{
  const int i = blockIdx.x * 256 + threadIdx.x;  // 0 .. 64*4096-1
  float f = w[i];
  unsigned short h = __builtin_bit_cast(unsigned short, __float2bfloat16(f));
  float hf = __uint_as_float(((unsigned)h) << 16);
  unsigned short l = __builtin_bit_cast(unsigned short, __float2bfloat16(f - hf));
  whi[i] = h;
  wlo[i] = l;
}

__global__ __launch_bounds__(512, 4) void router_kernel(
    const float* __restrict__ x,
    const unsigned short* __restrict__ whi, const unsigned short* __restrict__ wlo,
    float* __restrict__ out, float* __restrict__ ws)
{
  // 4 plane-buffers of bf16 x-tile: [hi|lo][buf0|buf1][32][LDX]  (34.8 KB)
  // after the K-loop the same memory is reused as 2 float logit buffers [32][65]
  __shared__ __align__(16) unsigned short smem[4 * XBUF];
#define XH(b) (smem + (b) * XBUF)
#define XL(b) (smem + (2 + (b)) * XBUF)

  const int tid  = threadIdx.x;
  const int lane = tid & 63;
  const int wv   = __builtin_amdgcn_readfirstlane(tid >> 6);  // 0..7, wave-uniform
  const int q    = wv & 3;   // expert quarter (16 experts)
  const int kh   = wv >> 2;  // BK-half: 0 or 1
  const int half = lane >> 4;  // 0..3
  const int r15  = lane & 15;
  const int tok0 = blockIdx.x * TOKB;

  // staging coords: thread t handles row t/16, cols (t%16)*8 .. +7 of the [32][128] tile
  const int   srow = tid >> 4;
  const int   scol = (tid & 15) * 8;
  const float* sp  = x + (size_t)(tok0 + srow) * DIM + scol;

  // w fragment base (this wave's 16 experts, its BK-half, this lane's k-subblock)
  const unsigned short* wh0 = whi + (size_t)(q * 16 + r15) * DIM + kh * 64 + half * 8;
  const unsigned short* wl0 = wlo + (size_t)(q * 16 + r15) * DIM + kh * 64 + half * 8;

  f32x4 acc[2];
#pragma unroll
  for (int t = 0; t < 2; ++t) acc[t] = (f32x4){0.f, 0.f, 0.f, 0.f};

  // prologue: stage tile 0 into buf 0
  {
    float4 f0 = *(const float4*)(sp);
    float4 f1 = *(const float4*)(sp + 4);
    bf16x8 h, l;
    split8(f0, f1, h, l);
    *(bf16x8*)(XH(0) + srow * LDX + scol) = h;
    *(bf16x8*)(XL(0) + srow * LDX + scol) = l;
  }
  __syncthreads();

  int cur = 0;
  for (int it = 0; it < NIT; ++it) {
    // issue next tile's global loads first (8 floats/thread)
    const size_t kn = (size_t)((it + 1 < NIT) ? (it + 1) : it) * BK;
    float4 f0 = *(const float4*)(sp + kn);
    float4 f1 = *(const float4*)(sp + kn + 4);

    // w fragments for this iter (L2-resident)
    const unsigned short* whk = wh0 + (size_t)it * BK;
    const unsigned short* wlk = wl0 + (size_t)it * BK;
    bf16x8 bh0 = *(const bf16x8*)(whk);
    bf16x8 bl0 = *(const bf16x8*)(wlk);
    bf16x8 bh1 = *(const bf16x8*)(whk + 32);
    bf16x8 bl1 = *(const bf16x8*)(wlk + 32);

    // x fragments from LDS + 12 MFMA (2 token-tiles x 2 k-steps x 3 passes)
    const unsigned short* xhb = XH(cur) + kh * 64 + half * 8;
    const unsigned short* xlb = XL(cur) + kh * 64 + half * 8;
#pragma unroll
    for (int tt = 0; tt < 2; ++tt) {
      const int ro = (tt * 16 + r15) * LDX;
      bf16x8 ah0 = *(const bf16x8*)(xhb + ro);
      bf16x8 al0 = *(const bf16x8*)(xlb + ro);
      bf16x8 ah1 = *(const bf16x8*)(xhb + ro + 32);
      bf16x8 al1 = *(const bf16x8*)(xlb + ro + 32);
      acc[tt] = __builtin_amdgcn_mfma_f32_16x16x32_bf16(ah0, bh0, acc[tt], 0, 0, 0);
      acc[tt] = __builtin_amdgcn_mfma_f32_16x16x32_bf16(al0, bh0, acc[tt], 0, 0, 0);
      acc[tt] = __builtin_amdgcn_mfma_f32_16x16x32_bf16(ah0, bl0, acc[tt], 0, 0, 0);
      acc[tt] = __builtin_amdgcn_mfma_f32_16x16x32_bf16(ah1, bh1, acc[tt], 0, 0, 0);
      acc[tt] = __builtin_amdgcn_mfma_f32_16x16x32_bf16(al1, bh1, acc[tt], 0, 0, 0);
      acc[tt] = __builtin_amdgcn_mfma_f32_16x16x32_bf16(ah1, bl1, acc[tt], 0, 0, 0);
    }

    // stage next tile into the other buffer
    bf16x8 h, l;
    split8(f0, f1, h, l);
    *(bf16x8*)(XH(cur ^ 1) + srow * LDX + scol) = h;
    *(bf16x8*)(XL(cur ^ 1) + srow * LDX + scol) = l;
    __syncthreads();
    cur ^= 1;
  }

  // ---- epilogue: reuse smem as two float logit buffers [32][65] ----
  float* lb = (float*)smem;
  {
    float* dst = lb + kh * (TOKB * 65);
#pragma unroll
    for (int tt = 0; tt < 2; ++tt) {
#pragma unroll
      for (int r = 0; r < 4; ++r) {
        dst[(tt * 16 + half * 4 + r) * 65 + q * 16 + r15] = acc[tt][r];
      }
    }
  }
  __syncthreads();

  // combine the two BK-half partials
  for (int i = tid; i < TOKB * 64; i += 512) {
    const int t = i >> 6, e = i & 63;
    lb[t * 65 + e] += lb[TOKB * 65 + t * 65 + e];
  }
  __syncthreads();

  if (wv == 0 && lane < TOKB) {
    // lane owns one token: full softmax + top-2 + z-loss
    const int token = tok0 + lane;
    float v[64];
#pragma unroll
    for (int e = 0; e < 64; ++e) v[e] = lb[lane * 65 + e];
    float m = v[0];
#pragma unroll
    for (int e = 1; e < 64; ++e) m = fmaxf(m, v[e]);
    float sum = 0.f;
#pragma unroll
    for (int e = 0; e < 64; ++e) { v[e] = expf(v[e] - m); sum += v[e]; }
    const float inv = 1.0f / sum;
    float m1 = -1.f, m2 = -1.f;
    int   i1 = 0,    i2 = 0;
#pragma unroll
    for (int e = 0; e < 64; ++e) {
      float sc = v[e] * inv;
      lb[lane * 65 + e] = sc;
      if (sc > m1)      { m2 = m1; i2 = i1; m1 = sc; i1 = e; }
      else if (sc > m2) { m2 = sc; i2 = e; }
    }
    out[2 * token]         = (float)i1;
    out[2 * token + 1]     = (float)i2;
    out[OFF_W + 2 * token]     = m1;
    out[OFF_W + 2 * token + 1] = m2;

    float lse = m + logf(sum);
    float z = lse * lse;
#pragma unroll
    for (int off = 16; off > 0; off >>= 1) z += __shfl_down(z, off);
    if (lane == 0) atomicAdd(ws + 128, z);
  }
  __syncthreads();

  // coalesced scores store for this block's 32 tokens
  float* outS = out + OFF_S + (size_t)blockIdx.x * TOKB * 64;
  for (int i = tid; i < TOKB * 64; i += 512) {
    outS[i] = lb[(i >> 6) * 65 + (i & 63)];
  }

  // per-expert partial me / ce for this block's tokens (expert = lane)
  if (wv == 0) {
    float sm = 0.f, cn = 0.f;
#pragma unroll
    for (int t = 0; t < TOKB; ++t) {
      float sc = lb[t * 65 + lane];
      sm += sc;
      cn += (sc > 0.f) ? 1.f : 0.f;
    }
    atomicAdd(ws + lane, sm);
    atomicAdd(ws + 64 + lane, cn);
  }
#undef XH
#undef XL
}

__global__ void finalize_kernel(const float* __restrict__ ws, float* __restrict__ out) {
  const int l = threadIdx.x;  // 64 threads
  const float invT = 1.0f / (float)N_TOKENS;
  float me = ws[l] * invT;
  float ce = ws[64 + l] * invT;
  float p = me * ce;
#pragma unroll
  for (int off = 32; off > 0; off >>= 1) p += __shfl_down(p, off);
  if (l == 0) {
    out[OFF_LBL] = p * (float)N_EXP;
    out[OFF_Z]   = ws[128] * invT;
  }
}

extern "C" void kernel_launch(void* const* d_in, const int* in_sizes, int n_in,
                              void* d_out, int out_size, void* d_ws, size_t ws_size,
                              hipStream_t stream) {
  const float* x = (const float*)d_in[0];
  const float* w = (const float*)d_in[1];
  float* out = (float*)d_out;
  float* ws  = (float*)d_ws;
  unsigned short* whi = (unsigned short*)(ws + WS_WHI_F);
  unsigned short* wlo = (unsigned short*)(ws + WS_WLO_F);

  (void)hipMemsetAsync(d_ws, 0, 129 * sizeof(float), stream);
  split_w_kernel<<<(N_EXP * DIM) / 256, 256, 0, stream>>>(w, whi, wlo);
  router_kernel<<<N_TOKENS / TOKB, 512, 0, stream>>>(x, whi, wlo, out, ws);
  finalize_kernel<<<1, 64, 0, stream>>>(ws, out);
}

// Round 10
// 106.489 us; speedup vs baseline: 1.6954x; 1.0324x over previous
//
#include <hip/hip_runtime.h>
#include <hip/hip_bf16.h>

typedef __attribute__((ext_vector_type(8))) short bf16x8;
typedef __attribute__((ext_vector_type(4))) float f32x4;

#define N_TOKENS 16384
#define DIM 4096
#define TOKB 32            // tokens per block
#define BK 128             // K per staged tile
#define NIT (DIM / BK)     // 32 iterations
#define LDX 136            // bf16 row stride in LDS (128 + 8 pad)
#define XBUF (TOKB * LDX)  // 4352 ushorts per plane-buffer
#define N_EXP 64

// d_out layout (all float32):
//   [0, 32768)              topk_experts as float  [token][2]
//   [32768, 65536)          combine_weight         [token][2]
//   [65536, 65536+1048576)  scores                 [token][64]
//   [1114112]               load_balance_loss
//   [1114113]               z_loss
#define OFF_W   (N_TOKENS * 2)
#define OFF_S   (N_TOKENS * 4)
#define OFF_LBL (N_TOKENS * 4 + N_TOKENS * N_EXP)
#define OFF_Z   (OFF_LBL + 1)

// ws layout (floats): [0..63] me partials, [64..127] ce partials, [128] z partial,
// [512 ..) w_hi as ushort[64*4096] (512 KB), then w_lo as ushort[64*4096] (512 KB)
#define WS_WHI_F 512
#define WS_WLO_F (512 + (N_EXP * DIM) / 2)

// split one fp32 into hi bf16 + lo bf16 (RNE both): f ≈ hi + lo, |err| ~ 2^-17 |f|
__device__ __forceinline__ void split2(float f, short* hi, short* lo) {
  unsigned short h = __builtin_bit_cast(unsigned short, __float2bfloat16(f));
  float hf = __uint_as_float(((unsigned)h) << 16);
  unsigned short l = __builtin_bit_cast(unsigned short, __float2bfloat16(f - hf));
  *hi = (short)h;
  *lo = (short)l;
}

__device__ __forceinline__ void split8(const float4& f0, const float4& f1,
                                       bf16x8& hi, bf16x8& lo) {
  short h[8], l[8];
  split2(f0.x, &h[0], &l[0]);
  split2(f0.y, &h[1], &l[1]);
  split2(f0.z, &h[2], &l[2]);
  split2(f0.w, &h[3], &l[3]);
  split2(f1.x, &h[4], &l[4]);
  split2(f1.y, &h[5], &l[5]);
  split2(f1.z, &h[6], &l[6]);
  split2(f1.w, &h[7], &l[7]);
#pragma unroll
  for (int i = 0; i < 8; ++i) { hi[i] = h[i]; lo[i] = l[i]; }
}

// pre-pass: w fp32 -> separate bf16 hi / lo planes (1 MB total, ~3 us)
__global__ __launch_bounds__(256) void split_w_kernel(
    const float* __restrict__ w,
    unsigned short* __restrict__ whi, unsigned short* __restrict__ wlo)
{
  const int i = blockIdx.x * 256 + threadIdx.x;  // 0 .. 64*4096-1
  float f = w[i];
  unsigned short h = __builtin_bit_cast(unsigned short, __float2bfloat16(f));
  float hf = __uint_as_float(((unsigned)h) << 16);
  unsigned short l = __builtin_bit_cast(unsigned short, __float2bfloat16(f - hf));
  whi[i] = h;
  wlo[i] = l;
}

__global__ __launch_bounds__(512, 4) void router_kernel(
    const float* __restrict__ x,
    const unsigned short* __restrict__ whi, const unsigned short* __restrict__ wlo,
    float* __restrict__ out, float* __restrict__ ws)
{
  // 4 plane-buffers of bf16 x-tile: [hi|lo][buf0|buf1][32][LDX]  (34.8 KB)
  // after the K-loop the same memory is reused as 2 float logit buffers [32][65]
  __shared__ __align__(16) unsigned short smem[4 * XBUF];
#define XH(b) (smem + (b) * XBUF)
#define XL(b) (smem + (2 + (b)) * XBUF)

  const int tid  = threadIdx.x;
  const int lane = tid & 63;
  const int wv   = __builtin_amdgcn_readfirstlane(tid >> 6);  // 0..7, wave-uniform
  const int q    = wv & 3;   // expert quarter (16 experts)
  const int kh   = wv >> 2;  // BK-half: 0 or 1
  const int half = lane >> 4;  // 0..3
  const int r15  = lane & 15;
  const int tok0 = blockIdx.x * TOKB;

  // staging coords: thread t handles row t/16, cols (t%16)*8 .. +7 of the [32][128] tile
  const int   srow = tid >> 4;
  const int   scol = (tid & 15) * 8;
  const float* sp  = x + (size_t)(tok0 + srow) * DIM + scol;

  // w fragment base (this wave's 16 experts, its BK-half, this lane's k-subblock)
  const unsigned short* wh0 = whi + (size_t)(q * 16 + r15) * DIM + kh * 64 + half * 8;
  const unsigned short* wl0 = wlo + (size_t)(q * 16 + r15) * DIM + kh * 64 + half * 8;

  f32x4 acc[2];
#pragma unroll
  for (int t = 0; t < 2; ++t) acc[t] = (f32x4){0.f, 0.f, 0.f, 0.f};

  // prologue: stage tile 0 into buf 0; pre-load tile 1 into hold regs
  {
    float4 f0 = *(const float4*)(sp);
    float4 f1 = *(const float4*)(sp + 4);
    bf16x8 h, l;
    split8(f0, f1, h, l);
    *(bf16x8*)(XH(0) + srow * LDX + scol) = h;
    *(bf16x8*)(XL(0) + srow * LDX + scol) = l;
  }
  float4 h0 = *(const float4*)(sp + BK);
  float4 h1 = *(const float4*)(sp + BK + 4);
  asm volatile("s_waitcnt lgkmcnt(0)" ::: "memory");
  __builtin_amdgcn_s_barrier();

  int cur = 0;
  for (int it = 0; it < NIT; ++it) {
    // prefetch tile it+2 (2-deep; consumed next iteration)
    const size_t kn2 = (size_t)((it + 2 < NIT) ? (it + 2) : (NIT - 1)) * BK;
    float4 n0 = *(const float4*)(sp + kn2);
    float4 n1 = *(const float4*)(sp + kn2 + 4);

    // w fragments for this iter (L2-resident)
    const unsigned short* whk = wh0 + (size_t)it * BK;
    const unsigned short* wlk = wl0 + (size_t)it * BK;
    bf16x8 bh0 = *(const bf16x8*)(whk);
    bf16x8 bl0 = *(const bf16x8*)(wlk);
    bf16x8 bh1 = *(const bf16x8*)(whk + 32);
    bf16x8 bl1 = *(const bf16x8*)(wlk + 32);

    // x fragments from LDS + 12 MFMA (2 token-tiles x 2 k-steps x 3 passes)
    const unsigned short* xhb = XH(cur) + kh * 64 + half * 8;
    const unsigned short* xlb = XL(cur) + kh * 64 + half * 8;
#pragma unroll
    for (int tt = 0; tt < 2; ++tt) {
      const int ro = (tt * 16 + r15) * LDX;
      bf16x8 ah0 = *(const bf16x8*)(xhb + ro);
      bf16x8 al0 = *(const bf16x8*)(xlb + ro);
      bf16x8 ah1 = *(const bf16x8*)(xhb + ro + 32);
      bf16x8 al1 = *(const bf16x8*)(xlb + ro + 32);
      acc[tt] = __builtin_amdgcn_mfma_f32_16x16x32_bf16(ah0, bh0, acc[tt], 0, 0, 0);
      acc[tt] = __builtin_amdgcn_mfma_f32_16x16x32_bf16(al0, bh0, acc[tt], 0, 0, 0);
      acc[tt] = __builtin_amdgcn_mfma_f32_16x16x32_bf16(ah0, bl0, acc[tt], 0, 0, 0);
      acc[tt] = __builtin_amdgcn_mfma_f32_16x16x32_bf16(ah1, bh1, acc[tt], 0, 0, 0);
      acc[tt] = __builtin_amdgcn_mfma_f32_16x16x32_bf16(al1, bh1, acc[tt], 0, 0, 0);
      acc[tt] = __builtin_amdgcn_mfma_f32_16x16x32_bf16(ah1, bl1, acc[tt], 0, 0, 0);
    }

    // split the HELD tile (it+1, loaded last iteration) and stage it
    {
      bf16x8 h, l;
      split8(h0, h1, h, l);
      *(bf16x8*)(XH(cur ^ 1) + srow * LDX + scol) = h;
      *(bf16x8*)(XL(cur ^ 1) + srow * LDX + scol) = l;
    }
    // lgkm-only barrier: LDS ordering without draining global prefetches
    asm volatile("s_waitcnt lgkmcnt(0)" ::: "memory");
    __builtin_amdgcn_s_barrier();

    h0 = n0; h1 = n1;
    cur ^= 1;
  }

  // ---- epilogue: reuse smem as two float logit buffers [32][65] ----
  float* lb = (float*)smem;
  {
    float* dst = lb + kh * (TOKB * 65);
#pragma unroll
    for (int tt = 0; tt < 2; ++tt) {
#pragma unroll
      for (int r = 0; r < 4; ++r) {
        dst[(tt * 16 + half * 4 + r) * 65 + q * 16 + r15] = acc[tt][r];
      }
    }
  }
  __syncthreads();

  // combine the two BK-half partials
  for (int i = tid; i < TOKB * 64; i += 512) {
    const int t = i >> 6, e = i & 63;
    lb[t * 65 + e] += lb[TOKB * 65 + t * 65 + e];
  }
  __syncthreads();

  if (wv == 0 && lane < TOKB) {
    // lane owns one token: full softmax + top-2 + z-loss
    const int token = tok0 + lane;
    float v[64];
#pragma unroll
    for (int e = 0; e < 64; ++e) v[e] = lb[lane * 65 + e];
    float m = v[0];
#pragma unroll
    for (int e = 1; e < 64; ++e) m = fmaxf(m, v[e]);
    float sum = 0.f;
#pragma unroll
    for (int e = 0; e < 64; ++e) { v[e] = expf(v[e] - m); sum += v[e]; }
    const float inv = 1.0f / sum;
    float m1 = -1.f, m2 = -1.f;
    int   i1 = 0,    i2 = 0;
#pragma unroll
    for (int e = 0; e < 64; ++e) {
      float sc = v[e] * inv;
      lb[lane * 65 + e] = sc;
      if (sc > m1)      { m2 = m1; i2 = i1; m1 = sc; i1 = e; }
      else if (sc > m2) { m2 = sc; i2 = e; }
    }
    out[2 * token]         = (float)i1;
    out[2 * token + 1]     = (float)i2;
    out[OFF_W + 2 * token]     = m1;
    out[OFF_W + 2 * token + 1] = m2;

    float lse = m + logf(sum);
    float z = lse * lse;
#pragma unroll
    for (int off = 16; off > 0; off >>= 1) z += __shfl_down(z, off);
    if (lane == 0) atomicAdd(ws + 128, z);
  }
  __syncthreads();

  // coalesced scores store for this block's 32 tokens
  float* outS = out + OFF_S + (size_t)blockIdx.x * TOKB * 64;
  for (int i = tid; i < TOKB * 64; i += 512) {
    outS[i] = lb[(i >> 6) * 65 + (i & 63)];
  }

  // per-expert partial me / ce for this block's tokens (expert = lane)
  if (wv == 0) {
    float sm = 0.f, cn = 0.f;
#pragma unroll
    for (int t = 0; t < TOKB; ++t) {
      float sc = lb[t * 65 + lane];
      sm += sc;
      cn += (sc > 0.f) ? 1.f : 0.f;
    }
    atomicAdd(ws + lane, sm);
    atomicAdd(ws + 64 + lane, cn);
  }
#undef XH
#undef XL
}

__global__ void finalize_kernel(const float* __restrict__ ws, float* __restrict__ out) {
  const int l = threadIdx.x;  // 64 threads
  const float invT = 1.0f / (float)N_TOKENS;
  float me = ws[l] * invT;
  float ce = ws[64 + l] * invT;
  float p = me * ce;
#pragma unroll
  for (int off = 32; off > 0; off >>= 1) p += __shfl_down(p, off);
  if (l == 0) {
    out[OFF_LBL] = p * (float)N_EXP;
    out[OFF_Z]   = ws[128] * invT;
  }
}

extern "C" void kernel_launch(void* const* d_in, const int* in_sizes, int n_in,
                              void* d_out, int out_size, void* d_ws, size_t ws_size,
                              hipStream_t stream) {
  const float* x = (const float*)d_in[0];
  const float* w = (const float*)d_in[1];
  float* out = (float*)d_out;
  float* ws  = (float*)d_ws;
  unsigned short* whi = (unsigned short*)(ws + WS_WHI_F);
  unsigned short* wlo = (unsigned short*)(ws + WS_WLO_F);

  (void)hipMemsetAsync(d_ws, 0, 129 * sizeof(float), stream);
  split_w_kernel<<<(N_EXP * DIM) / 256, 256, 0, stream>>>(w, whi, wlo);
  router_kernel<<<N_TOKENS / TOKB, 512, 0, stream>>>(x, whi, wlo, out, ws);
  finalize_kernel<<<1, 64, 0, stream>>>(ws, out);
}

// Round 11
// 101.914 us; speedup vs baseline: 1.7715x; 1.0449x over previous
//
#include <hip/hip_runtime.h>
#include <hip/hip_bf16.h>

typedef __attribute__((ext_vector_type(8))) short bf16x8;
typedef __attribute__((ext_vector_type(4))) float f32x4;

#define N_TOKENS 16384
#define DIM 4096
#define TOKB 32            // tokens per block
#define BK 128             // K floats per staged tile
#define NIT (DIM / BK)     // 32 iterations
#define NBUF 4
#define BUF_F (TOKB * BK)  // 4096 floats (16 KB) per buffer
#define N_EXP 64

// d_out layout (all float32):
//   [0, 32768)              topk_experts as float  [token][2]
//   [32768, 65536)          combine_weight         [token][2]
//   [65536, 65536+1048576)  scores                 [token][64]
//   [1114112]               load_balance_loss
//   [1114113]               z_loss
#define OFF_W   (N_TOKENS * 2)
#define OFF_S   (N_TOKENS * 4)
#define OFF_LBL (N_TOKENS * 4 + N_TOKENS * N_EXP)
#define OFF_Z   (OFF_LBL + 1)

// ws layout (floats): [0..63] me partials, [64..127] ce partials, [128] z partial,
// [512 ..) w_hi as ushort[64*4096] (512 KB), then w_lo as ushort[64*4096] (512 KB)
#define WS_WHI_F 512
#define WS_WLO_F (512 + (N_EXP * DIM) / 2)

typedef const __attribute__((address_space(1))) void GV;
typedef __attribute__((address_space(3))) void LV;

// split one fp32 into hi bf16 + lo bf16 (RNE both): f ≈ hi + lo, |err| ~ 2^-17 |f|
__device__ __forceinline__ void split2(float f, short* hi, short* lo) {
  unsigned short h = __builtin_bit_cast(unsigned short, __float2bfloat16(f));
  float hf = __uint_as_float(((unsigned)h) << 16);
  unsigned short l = __builtin_bit_cast(unsigned short, __float2bfloat16(f - hf));
  *hi = (short)h;
  *lo = (short)l;
}

__device__ __forceinline__ void split8v(const f32x4& f0, const f32x4& f1,
                                        bf16x8& hi, bf16x8& lo) {
  short h[8], l[8];
  split2(f0[0], &h[0], &l[0]);
  split2(f0[1], &h[1], &l[1]);
  split2(f0[2], &h[2], &l[2]);
  split2(f0[3], &h[3], &l[3]);
  split2(f1[0], &h[4], &l[4]);
  split2(f1[1], &h[5], &l[5]);
  split2(f1[2], &h[6], &l[6]);
  split2(f1[3], &h[7], &l[7]);
#pragma unroll
  for (int i = 0; i < 8; ++i) { hi[i] = h[i]; lo[i] = l[i]; }
}

// pre-pass: w fp32 -> separate bf16 hi / lo planes (1 MB total, ~3 us)
__global__ __launch_bounds__(256) void split_w_kernel(
    const float* __restrict__ w,
    unsigned short* __restrict__ whi, unsigned short* __restrict__ wlo)
{
  const int i = blockIdx.x * 256 + threadIdx.x;  // 0 .. 64*4096-1
  float f = w[i];
  unsigned short h = __builtin_bit_cast(unsigned short, __float2bfloat16(f));
  float hf = __uint_as_float(((unsigned)h) << 16);
  unsigned short l = __builtin_bit_cast(unsigned short, __float2bfloat16(f - hf));
  whi[i] = h;
  wlo[i] = l;
}

__global__ __launch_bounds__(512, 4) void router_kernel(
    const float* __restrict__ x,
    const unsigned short* __restrict__ whi, const unsigned short* __restrict__ wlo,
    float* __restrict__ out, float* __restrict__ ws)
{
  // 4 linear fp32 x-tile buffers [32][128] (64 KB); reused as logits in epilogue.
  // Content is source-swizzled at 16B granularity: LDS[row][u] = x[row][u ^ (row&7)]
  __shared__ __align__(16) float smem[NBUF * BUF_F];

  const int tid  = threadIdx.x;
  const int lane = tid & 63;
  const int wv   = __builtin_amdgcn_readfirstlane(tid >> 6);  // 0..7, wave-uniform
  const int q    = wv & 3;     // expert quarter (16 experts)
  const int kh   = wv >> 2;    // BK-half: 0 or 1
  const int half = lane >> 4;  // 0..3
  const int r15  = lane & 15;
  const int tok0 = blockIdx.x * TOKB;

  // staging: wave wv covers bytes [wv*2048, wv*2048+2048) of the 16 KB tile,
  // via 2 global_load_lds (1 KB each: lane writes 16 B at ldsbase + lane*16).
  // instr i: row = wv*4 + i*2 + (lane>>5), 16B-unit u = lane&31,
  // source unit = u ^ (row&7)  (inverse swizzle; involution)
  const int row0 = wv * 4 + (lane >> 5);
  const int row1 = row0 + 2;
  const int sU   = lane & 31;
  const float* g0 = x + (size_t)(tok0 + row0) * DIM + ((sU ^ (row0 & 7)) << 2);
  const float* g1 = x + (size_t)(tok0 + row1) * DIM + ((sU ^ (row1 & 7)) << 2);
  float* const ldst = smem + wv * 512;  // wave-uniform

#define STAGE(buf, it_) do {                                                  \
    const float* s0_ = g0 + (size_t)(it_) * BK;                               \
    const float* s1_ = g1 + (size_t)(it_) * BK;                               \
    float* d_ = ldst + (buf) * BUF_F;                                         \
    __builtin_amdgcn_global_load_lds((GV*)s0_, (LV*)d_,       16, 0, 0);      \
    __builtin_amdgcn_global_load_lds((GV*)s1_, (LV*)(d_+256), 16, 0, 0);      \
  } while (0)

  // w fragment base (this wave's 16 experts, its BK-half, this lane's k-subblock)
  const unsigned short* wh0 = whi + (size_t)(q * 16 + r15) * DIM + kh * 64 + half * 8;
  const unsigned short* wl0 = wlo + (size_t)(q * 16 + r15) * DIM + kh * 64 + half * 8;

  f32x4 acc[2];
#pragma unroll
  for (int t = 0; t < 2; ++t) acc[t] = (f32x4){0.f, 0.f, 0.f, 0.f};

  // ---- prologue: FIFO = stage0(2), w0(4), stage1(2) ----
  STAGE(0, 0);
  bf16x8 cbh0 = *(const bf16x8*)(wh0);
  bf16x8 cbl0 = *(const bf16x8*)(wl0);
  bf16x8 cbh1 = *(const bf16x8*)(wh0 + 32);
  bf16x8 cbl1 = *(const bf16x8*)(wl0 + 32);
  STAGE(1, 1);

  for (int it = 0; it < NIT; ++it) {
    const int cur = it & 3;
    // w_{it+1} prefetch (clamped) -- 4 vmem ops
    const size_t kwn = (size_t)((it + 1 < NIT) ? it + 1 : NIT - 1) * BK;
    bf16x8 nbh0 = *(const bf16x8*)(wh0 + kwn);
    bf16x8 nbl0 = *(const bf16x8*)(wl0 + kwn);
    bf16x8 nbh1 = *(const bf16x8*)(wh0 + kwn + 32);
    bf16x8 nbl1 = *(const bf16x8*)(wl0 + kwn + 32);
    // stage it+2 (clamped) -- 2 vmem ops
    STAGE((it + 2) & 3, (it + 2 < NIT) ? it + 2 : NIT - 1);

    // everything issued BEFORE this iteration's 6 vmem ops must be retired:
    // guarantees stage(it) landed in LDS and w_it (already in regs) valid.
    asm volatile("s_waitcnt vmcnt(6)" ::: "memory");
    __builtin_amdgcn_s_barrier();

    // ---- compute from buf cur (swizzled fp32 reads -> split -> 12 MFMA) ----
    const float* bufp = smem + cur * BUF_F;
#pragma unroll
    for (int tt = 0; tt < 2; ++tt) {
      const int rowA = tt * 16 + r15;
      const int g    = rowA & 7;
      const float* rp = bufp + rowA * BK;
#pragma unroll
      for (int j = 0; j < 2; ++j) {
        const int sA = kh * 16 + j * 8 + half * 2;
        f32x4 p0 = *(const f32x4*)(rp + (((sA)     ^ g) << 2));
        f32x4 p1 = *(const f32x4*)(rp + (((sA + 1) ^ g) << 2));
        bf16x8 ah, al;
        split8v(p0, p1, ah, al);
        const bf16x8 bh = j ? cbh1 : cbh0;
        const bf16x8 bl = j ? cbl1 : cbl0;
        acc[tt] = __builtin_amdgcn_mfma_f32_16x16x32_bf16(ah, bh, acc[tt], 0, 0, 0);
        acc[tt] = __builtin_amdgcn_mfma_f32_16x16x32_bf16(al, bh, acc[tt], 0, 0, 0);
        acc[tt] = __builtin_amdgcn_mfma_f32_16x16x32_bf16(ah, bl, acc[tt], 0, 0, 0);
      }
    }

    cbh0 = nbh0; cbl0 = nbl0; cbh1 = nbh1; cbl1 = nbl1;
  }

  // drain all outstanding gll writes (incl. clamped tail stages into buf0/buf1)
  // before reusing smem as the logits buffer
  __syncthreads();

  // ---- epilogue: reuse smem as two float logit buffers [32][65] ----
  float* lb = smem;
  {
    float* dst = lb + kh * (TOKB * 65);
#pragma unroll
    for (int tt = 0; tt < 2; ++tt) {
#pragma unroll
      for (int r = 0; r < 4; ++r) {
        dst[(tt * 16 + half * 4 + r) * 65 + q * 16 + r15] = acc[tt][r];
      }
    }
  }
  __syncthreads();

  // combine the two BK-half partials
  for (int i = tid; i < TOKB * 64; i += 512) {
    const int t = i >> 6, e = i & 63;
    lb[t * 65 + e] += lb[TOKB * 65 + t * 65 + e];
  }
  __syncthreads();

  if (wv == 0 && lane < TOKB) {
    // lane owns one token: full softmax + top-2 + z-loss
    const int token = tok0 + lane;
    float v[64];
#pragma unroll
    for (int e = 0; e < 64; ++e) v[e] = lb[lane * 65 + e];
    float m = v[0];
#pragma unroll
    for (int e = 1; e < 64; ++e) m = fmaxf(m, v[e]);
    float sum = 0.f;
#pragma unroll
    for (int e = 0; e < 64; ++e) { v[e] = expf(v[e] - m); sum += v[e]; }
    const float inv = 1.0f / sum;
    float m1 = -1.f, m2 = -1.f;
    int   i1 = 0,    i2 = 0;
#pragma unroll
    for (int e = 0; e < 64; ++e) {
      float sc = v[e] * inv;
      lb[lane * 65 + e] = sc;
      if (sc > m1)      { m2 = m1; i2 = i1; m1 = sc; i1 = e; }
      else if (sc > m2) { m2 = sc; i2 = e; }
    }
    out[2 * token]         = (float)i1;
    out[2 * token + 1]     = (float)i2;
    out[OFF_W + 2 * token]     = m1;
    out[OFF_W + 2 * token + 1] = m2;

    float lse = m + logf(sum);
    float z = lse * lse;
#pragma unroll
    for (int off = 16; off > 0; off >>= 1) z += __shfl_down(z, off);
    if (lane == 0) atomicAdd(ws + 128, z);
  }
  __syncthreads();

  // coalesced scores store for this block's 32 tokens
  float* outS = out + OFF_S + (size_t)blockIdx.x * TOKB * 64;
  for (int i = tid; i < TOKB * 64; i += 512) {
    outS[i] = lb[(i >> 6) * 65 + (i & 63)];
  }

  // per-expert partial me / ce for this block's tokens (expert = lane)
  if (wv == 0) {
    float sm = 0.f, cn = 0.f;
#pragma unroll
    for (int t = 0; t < TOKB; ++t) {
      float sc = lb[t * 65 + lane];
      sm += sc;
      cn += (sc > 0.f) ? 1.f : 0.f;
    }
    atomicAdd(ws + lane, sm);
    atomicAdd(ws + 64 + lane, cn);
  }
#undef STAGE
}

__global__ void finalize_kernel(const float* __restrict__ ws, float* __restrict__ out) {
  const int l = threadIdx.x;  // 64 threads
  const float invT = 1.0f / (float)N_TOKENS;
  float me = ws[l] * invT;
  float ce = ws[64 + l] * invT;
  float p = me * ce;
#pragma unroll
  for (int off = 32; off > 0; off >>= 1) p += __shfl_down(p, off);
  if (l == 0) {
    out[OFF_LBL] = p * (float)N_EXP;
    out[OFF_Z]   = ws[128] * invT;
  }
}

extern "C" void kernel_launch(void* const* d_in, const int* in_sizes, int n_in,
                              void* d_out, int out_size, void* d_ws, size_t ws_size,
                              hipStream_t stream) {
  const float* x = (const float*)d_in[0];
  const float* w = (const float*)d_in[1];
  float* out = (float*)d_out;
  float* ws  = (float*)d_ws;
  unsigned short* whi = (unsigned short*)(ws + WS_WHI_F);
  unsigned short* wlo = (unsigned short*)(ws + WS_WLO_F);

  (void)hipMemsetAsync(d_ws, 0, 129 * sizeof(float), stream);
  split_w_kernel<<<(N_EXP * DIM) / 256, 256, 0, stream>>>(w, whi, wlo);
  router_kernel<<<N_TOKENS / TOKB, 512, 0, stream>>>(x, whi, wlo, out, ws);
  finalize_kernel<<<1, 64, 0, stream>>>(ws, out);
}

// Round 12
// 99.943 us; speedup vs baseline: 1.8065x; 1.0197x over previous
//
#include <hip/hip_runtime.h>
#include <hip/hip_bf16.h>

typedef __attribute__((ext_vector_type(8))) short bf16x8;
typedef __attribute__((ext_vector_type(4))) float f32x4;

#define N_TOKENS 16384
#define DIM 4096
#define TOKB 32            // tokens per block
#define BK 128             // K floats per staged tile
#define NIT (DIM / BK)     // 32 iterations
#define NBUF 4
#define BUF_F (TOKB * BK)  // 4096 floats (16 KB) per buffer
#define N_EXP 64

// d_out layout (all float32):
//   [0, 32768)              topk_experts as float  [token][2]
//   [32768, 65536)          combine_weight         [token][2]
//   [65536, 65536+1048576)  scores                 [token][64]
//   [1114112]               load_balance_loss
//   [1114113]               z_loss
#define OFF_W   (N_TOKENS * 2)
#define OFF_S   (N_TOKENS * 4)
#define OFF_LBL (N_TOKENS * 4 + N_TOKENS * N_EXP)
#define OFF_Z   (OFF_LBL + 1)

// ws layout (floats): [0..63] me partials, [64..127] ce partials, [128] z partial,
// [512 ..) w_hi as ushort[64*4096] (512 KB), then w_lo as ushort[64*4096] (512 KB)
#define WS_WHI_F 512
#define WS_WLO_F (512 + (N_EXP * DIM) / 2)

typedef const __attribute__((address_space(1))) void GV;
typedef __attribute__((address_space(3))) void LV;

// ---- cheap truncation split: f = hi + r exactly at 8 mantissa bits; lo = trunc(r).
// 3 VALU/elem (perm-packed) vs ~12 for RNE. Residual error ~2^-16 |f|.
__device__ __forceinline__ unsigned int pkhi(float a, float b) {
  // dst = [hi16(b) : hi16(a)]  (element 0 = a)
  return __builtin_amdgcn_perm(__float_as_uint(b), __float_as_uint(a), 0x07060302u);
}
__device__ __forceinline__ float resid(float f) {
  return f - __uint_as_float(__float_as_uint(f) & 0xFFFF0000u);
}
__device__ __forceinline__ void tsplit8(const f32x4 p0, const f32x4 p1,
                                        bf16x8& hi, bf16x8& lo) {
  uint4 H = make_uint4(pkhi(p0[0], p0[1]), pkhi(p0[2], p0[3]),
                       pkhi(p1[0], p1[1]), pkhi(p1[2], p1[3]));
  float r0 = resid(p0[0]), r1 = resid(p0[1]), r2 = resid(p0[2]), r3 = resid(p0[3]);
  float r4 = resid(p1[0]), r5 = resid(p1[1]), r6 = resid(p1[2]), r7 = resid(p1[3]);
  uint4 L = make_uint4(pkhi(r0, r1), pkhi(r2, r3), pkhi(r4, r5), pkhi(r6, r7));
  hi = __builtin_bit_cast(bf16x8, H);
  lo = __builtin_bit_cast(bf16x8, L);
}

// pre-pass: w fp32 -> separate bf16 hi / lo planes (1 MB total, ~3 us); RNE is fine here
__global__ __launch_bounds__(256) void split_w_kernel(
    const float* __restrict__ w,
    unsigned short* __restrict__ whi, unsigned short* __restrict__ wlo)
{
  const int i = blockIdx.x * 256 + threadIdx.x;  // 0 .. 64*4096-1
  float f = w[i];
  unsigned short h = __builtin_bit_cast(unsigned short, __float2bfloat16(f));
  float hf = __uint_as_float(((unsigned)h) << 16);
  unsigned short l = __builtin_bit_cast(unsigned short, __float2bfloat16(f - hf));
  whi[i] = h;
  wlo[i] = l;
}

__global__ __launch_bounds__(512, 4) void router_kernel(
    const float* __restrict__ x,
    const unsigned short* __restrict__ whi, const unsigned short* __restrict__ wlo,
    float* __restrict__ out, float* __restrict__ ws)
{
  // 4 linear fp32 x-tile buffers [32][128] (64 KB); reused as logits in epilogue.
  // Content is source-swizzled at 16B granularity: LDS[row][u] = x[row][u ^ (row&7)]
  __shared__ __align__(16) float smem[NBUF * BUF_F];

  const int tid  = threadIdx.x;
  const int lane = tid & 63;
  const int wv   = __builtin_amdgcn_readfirstlane(tid >> 6);  // 0..7, wave-uniform
  const int q    = wv & 1;     // expert half (32 experts)
  const int kq   = wv >> 1;    // k-slice: 0..3 (32 floats each within BK)
  const int half = lane >> 4;  // 0..3
  const int r15  = lane & 15;
  const int tok0 = blockIdx.x * TOKB;

  // staging (identical to verified round-11 pattern): wave wv covers rows wv*4..+3
  const int row0 = wv * 4 + (lane >> 5);
  const int row1 = row0 + 2;
  const int sU   = lane & 31;
  const float* g0 = x + (size_t)(tok0 + row0) * DIM + ((sU ^ (row0 & 7)) << 2);
  const float* g1 = x + (size_t)(tok0 + row1) * DIM + ((sU ^ (row1 & 7)) << 2);
  float* const ldst = smem + wv * 512;  // wave-uniform

#define STAGE(buf, it_) do {                                                  \
    const float* s0_ = g0 + (size_t)(it_) * BK;                               \
    const float* s1_ = g1 + (size_t)(it_) * BK;                               \
    float* d_ = ldst + (buf) * BUF_F;                                         \
    __builtin_amdgcn_global_load_lds((GV*)s0_, (LV*)d_,       16, 0, 0);      \
    __builtin_amdgcn_global_load_lds((GV*)s1_, (LV*)(d_+256), 16, 0, 0);      \
  } while (0)

  // w fragment base: expert rows q*32 + n*16 + r15, k-offset kq*32 + half*8
  const unsigned short* wh0 = whi + (size_t)(q * 32 + r15) * DIM + kq * 32 + half * 8;
  const unsigned short* wl0 = wlo + (size_t)(q * 32 + r15) * DIM + kq * 32 + half * 8;

  f32x4 acc[2][2];
#pragma unroll
  for (int tt = 0; tt < 2; ++tt)
#pragma unroll
    for (int n = 0; n < 2; ++n) acc[tt][n] = (f32x4){0.f, 0.f, 0.f, 0.f};

  // ---- prologue: FIFO = stage0(2), w0(4), stage1(2) ----
  STAGE(0, 0);
  bf16x8 cbh[2], cbl[2];
#pragma unroll
  for (int n = 0; n < 2; ++n) {
    cbh[n] = *(const bf16x8*)(wh0 + (size_t)n * 16 * DIM);
    cbl[n] = *(const bf16x8*)(wl0 + (size_t)n * 16 * DIM);
  }
  STAGE(1, 1);

  for (int it = 0; it < NIT; ++it) {
    const int cur = it & 3;
    // w_{it+1} prefetch (clamped) -- 4 vmem ops
    const size_t kwn = (size_t)((it + 1 < NIT) ? it + 1 : NIT - 1) * BK;
    bf16x8 nbh[2], nbl[2];
#pragma unroll
    for (int n = 0; n < 2; ++n) {
      nbh[n] = *(const bf16x8*)(wh0 + kwn + (size_t)n * 16 * DIM);
      nbl[n] = *(const bf16x8*)(wl0 + kwn + (size_t)n * 16 * DIM);
    }
    // stage it+2 (clamped) -- 2 vmem ops
    STAGE((it + 2) & 3, (it + 2 < NIT) ? it + 2 : NIT - 1);

    // retire everything issued before this iteration's 6 vmem ops:
    // guarantees stage(it) landed in LDS (for every wave; barrier joins them).
    asm volatile("s_waitcnt vmcnt(6)" ::: "memory");
    __builtin_amdgcn_s_barrier();

    // ---- compute from buf cur: swizzled fp32 reads -> trunc-split -> 12 MFMA ----
    const float* bufp = smem + cur * BUF_F;
#pragma unroll
    for (int tt = 0; tt < 2; ++tt) {
      const int rowA = tt * 16 + r15;
      const int g    = r15 & 7;
      const float* rp = bufp + rowA * BK;
      const int u0 = (kq * 8 + half * 2) ^ g;
      const int u1 = (kq * 8 + half * 2 + 1) ^ g;
      f32x4 p0 = *(const f32x4*)(rp + (u0 << 2));
      f32x4 p1 = *(const f32x4*)(rp + (u1 << 2));
      bf16x8 ah, al;
      tsplit8(p0, p1, ah, al);
#pragma unroll
      for (int n = 0; n < 2; ++n) {
        acc[tt][n] = __builtin_amdgcn_mfma_f32_16x16x32_bf16(ah, cbh[n], acc[tt][n], 0, 0, 0);
        acc[tt][n] = __builtin_amdgcn_mfma_f32_16x16x32_bf16(al, cbh[n], acc[tt][n], 0, 0, 0);
        acc[tt][n] = __builtin_amdgcn_mfma_f32_16x16x32_bf16(ah, cbl[n], acc[tt][n], 0, 0, 0);
      }
    }

#pragma unroll
    for (int n = 0; n < 2; ++n) { cbh[n] = nbh[n]; cbl[n] = nbl[n]; }
  }

  // drain all outstanding gll writes (incl. clamped tail stages) before smem reuse
  __syncthreads();

  // ---- epilogue: reuse smem as 4 kq-partial logit buffers [32][65] ----
  float* lb = smem;
  {
    float* dst = lb + kq * (TOKB * 65);
#pragma unroll
    for (int tt = 0; tt < 2; ++tt) {
#pragma unroll
      for (int n = 0; n < 2; ++n) {
#pragma unroll
        for (int r = 0; r < 4; ++r) {
          dst[(tt * 16 + half * 4 + r) * 65 + q * 32 + n * 16 + r15] = acc[tt][n][r];
        }
      }
    }
  }
  __syncthreads();

  // combine the four kq partials
  for (int i = tid; i < TOKB * 64; i += 512) {
    const int t = i >> 6, e = i & 63;
    lb[t * 65 + e] += lb[2080 + t * 65 + e] + lb[4160 + t * 65 + e] + lb[6240 + t * 65 + e];
  }
  __syncthreads();

  if (wv == 0 && lane < TOKB) {
    // lane owns one token: full softmax + top-2 + z-loss
    const int token = tok0 + lane;
    float v[64];
#pragma unroll
    for (int e = 0; e < 64; ++e) v[e] = lb[lane * 65 + e];
    float m = v[0];
#pragma unroll
    for (int e = 1; e < 64; ++e) m = fmaxf(m, v[e]);
    float sum = 0.f;
#pragma unroll
    for (int e = 0; e < 64; ++e) { v[e] = expf(v[e] - m); sum += v[e]; }
    const float inv = 1.0f / sum;
    float m1 = -1.f, m2 = -1.f;
    int   i1 = 0,    i2 = 0;
#pragma unroll
    for (int e = 0; e < 64; ++e) {
      float sc = v[e] * inv;
      lb[lane * 65 + e] = sc;
      if (sc > m1)      { m2 = m1; i2 = i1; m1 = sc; i1 = e; }
      else if (sc > m2) { m2 = sc; i2 = e; }
    }
    out[2 * token]         = (float)i1;
    out[2 * token + 1]     = (float)i2;
    out[OFF_W + 2 * token]     = m1;
    out[OFF_W + 2 * token + 1] = m2;

    float lse = m + logf(sum);
    float z = lse * lse;
#pragma unroll
    for (int off = 16; off > 0; off >>= 1) z += __shfl_down(z, off);
    if (lane == 0) atomicAdd(ws + 128, z);
  }
  __syncthreads();

  // coalesced scores store for this block's 32 tokens
  float* outS = out + OFF_S + (size_t)blockIdx.x * TOKB * 64;
  for (int i = tid; i < TOKB * 64; i += 512) {
    outS[i] = lb[(i >> 6) * 65 + (i & 63)];
  }

  // per-expert partial me / ce for this block's tokens (expert = lane)
  if (wv == 0) {
    float sm = 0.f, cn = 0.f;
#pragma unroll
    for (int t = 0; t < TOKB; ++t) {
      float sc = lb[t * 65 + lane];
      sm += sc;
      cn += (sc > 0.f) ? 1.f : 0.f;
    }
    atomicAdd(ws + lane, sm);
    atomicAdd(ws + 64 + lane, cn);
  }
#undef STAGE
}

__global__ void finalize_kernel(const float* __restrict__ ws, float* __restrict__ out) {
  const int l = threadIdx.x;  // 64 threads
  const float invT = 1.0f / (float)N_TOKENS;
  float me = ws[l] * invT;
  float ce = ws[64 + l] * invT;
  float p = me * ce;
#pragma unroll
  for (int off = 32; off > 0; off >>= 1) p += __shfl_down(p, off);
  if (l == 0) {
    out[OFF_LBL] = p * (float)N_EXP;
    out[OFF_Z]   = ws[128] * invT;
  }
}

extern "C" void kernel_launch(void* const* d_in, const int* in_sizes, int n_in,
                              void* d_out, int out_size, void* d_ws, size_t ws_size,
                              hipStream_t stream) {
  const float* x = (const float*)d_in[0];
  const float* w = (const float*)d_in[1];
  float* out = (float*)d_out;
  float* ws  = (float*)d_ws;
  unsigned short* whi = (unsigned short*)(ws + WS_WHI_F);
  unsigned short* wlo = (unsigned short*)(ws + WS_WLO_F);

  (void)hipMemsetAsync(d_ws, 0, 129 * sizeof(float), stream);
  split_w_kernel<<<(N_EXP * DIM) / 256, 256, 0, stream>>>(w, whi, wlo);
  router_kernel<<<N_TOKENS / TOKB, 512, 0, stream>>>(x, whi, wlo, out, ws);
  finalize_kernel<<<1, 64, 0, stream>>>(ws, out);
}